// Round 3
// baseline (64.510 us; speedup 1.0000x reference)
//
#include <hip/hip_runtime.h>
#include <hip/hip_bf16.h>

// Closed form of the 16-qubit circuit (HW-validated in R2, absmax 4.9e-4):
//   ev[b,i] = prod_{k in S_i} cos(h[b,k]),  S_i = {k<=i : (i-k) mod 4 in {0,1}}
//   h = x@w_in^T + b_in;  out = ev@w_out^T + b_out.
// RZ phases (q_weights) cancel in |amp|^2; the CNOT-chain permutation cubed
// is the GF(2) map with coefficient C(i-k+2,2) mod 2 = [(i-k) mod 4 < 2].
// S_i = {i, i-1} ∪ S_{i-4}  =>  ev_i = c_i * c_{i-1} * ev_{i-4}.
//
// This version: one wave per batch row, zero LDS, zero barriers
// (wave-synchronous shuffles only), all-float4 loads.

#define NQ 16
#define D  128

__global__ __launch_bounds__(256) void qlayer_wave(
    const float* __restrict__ x,      // [B, 128]
    const float* __restrict__ w_in,   // [16, 128]
    const float* __restrict__ b_in,   // [16]
    const float* __restrict__ w_out,  // [128, 16]
    const float* __restrict__ b_out,  // [128]
    float* __restrict__ out)          // [B, 128]
{
    const int wave = threadIdx.x >> 6;            // 0..3
    const int lane = threadIdx.x & 63;
    const int b    = blockIdx.x * 4 + wave;       // one row per wave

    // ---- h_i = dot(x_row, w_in[i,:]) + b_in[i]; 4 lanes per i, 32 elems each
    const int i   = lane >> 2;                    // qubit 0..15
    const int seg = lane & 3;                     // 32-float segment
    const float4* xr = (const float4*)(x + b * D + seg * 32);
    const float4* wr = (const float4*)(w_in + i * D + seg * 32);
    float p = 0.f;
#pragma unroll
    for (int u = 0; u < 8; ++u) {
        float4 xv = xr[u], wv = wr[u];
        p += xv.x * wv.x + xv.y * wv.y + xv.z * wv.z + xv.w * wv.w;
    }
    p += __shfl_xor(p, 1);
    p += __shfl_xor(p, 2);                        // all 4 lanes of quad hold h_i partial sum
    const float c = cosf(p + b_in[i]);            // cos(h_i), held by quad i

    // ---- broadcast the 16 cosines to every lane
    float ck[NQ];
#pragma unroll
    for (int k = 0; k < NQ; ++k) ck[k] = __shfl(c, 4 * k);

    // ---- ev recurrence: ev_i = c_i * c_{i-1} * ev_{i-4}
    float ev[NQ];
    ev[0] = ck[0];
    ev[1] = ck[1] * ck[0];
    ev[2] = ck[2] * ck[1];
    ev[3] = ck[3] * ck[2];
#pragma unroll
    for (int q = 4; q < NQ; ++q) ev[q] = ck[q] * ck[q - 1] * ev[q - 4];

    // ---- out[b, j] = dot(ev, w_out[j,:]) + b_out[j], j = lane and lane+64
#pragma unroll
    for (int half = 0; half < 2; ++half) {
        const int j = lane + half * 64;
        const float4* wo = (const float4*)(w_out + j * NQ);
        float4 w0 = wo[0], w1 = wo[1], w2 = wo[2], w3 = wo[3];
        float o = b_out[j];
        o += ev[0]  * w0.x + ev[1]  * w0.y + ev[2]  * w0.z + ev[3]  * w0.w;
        o += ev[4]  * w1.x + ev[5]  * w1.y + ev[6]  * w1.z + ev[7]  * w1.w;
        o += ev[8]  * w2.x + ev[9]  * w2.y + ev[10] * w2.z + ev[11] * w2.w;
        o += ev[12] * w3.x + ev[13] * w3.y + ev[14] * w3.z + ev[15] * w3.w;
        out[b * D + j] = o;
    }
}

extern "C" void kernel_launch(void* const* d_in, const int* in_sizes, int n_in,
                              void* d_out, int out_size, void* d_ws, size_t ws_size,
                              hipStream_t stream) {
    const float* x     = (const float*)d_in[0];  // [512,128]
    const float* w_in  = (const float*)d_in[1];  // [16,128]
    const float* b_in  = (const float*)d_in[2];  // [16]
    // d_in[3] = q_weights — unused: RZ phases cancel in Z-basis probabilities.
    const float* w_out = (const float*)d_in[4];  // [128,16]
    const float* b_out = (const float*)d_in[5];  // [128]
    float* out = (float*)d_out;                  // [512,128]

    const int B = in_sizes[0] / D;               // 512 rows, 4 rows per block
    qlayer_wave<<<B / 4, 256, 0, stream>>>(x, w_in, b_in, w_out, b_out, out);
}